// Round 1
// baseline (4409.867 us; speedup 1.0000x reference)
//
#include <hip/hip_runtime.h>

// Problem constants (fixed by reference)
#define BB 4
#define HH 16
#define SS 2048
#define DD 64
#define BM 64
#define BN 64
#define NT 256

#define SCALE 0.125f
#define MASK_FILL -1e10f

__global__ __launch_bounds__(NT) void sdpa_fused_f32(
    const float* __restrict__ q, const float* __restrict__ k,
    const float* __restrict__ v, const int* __restrict__ mask,
    float* __restrict__ out, float* __restrict__ score)
{
    __shared__ float Qs[BM][DD];   // 16 KB
    __shared__ float Ks[DD][BN];   // 16 KB (k is pre-transposed: [d][s])
    __shared__ float Vs[BN][DD];   // 16 KB
    __shared__ float Ps[BM][BN];   // 16 KB  -> total 64 KB, 2 blocks/CU

    const int it  = blockIdx.x;            // q-row tile
    const int bh  = blockIdx.y;            // b*H + h
    const int b   = bh >> 4;               // H == 16
    const int tid = threadIdx.x;
    const int tx  = tid & 15;              // col group (16 lanes -> 64 cols via x4)
    const int ty  = tid >> 4;              // row group
    const int i0  = it * BM;

    const float* qbase = q + ((size_t)bh * SS + i0) * DD;
    const float* kbase = k + (size_t)bh * DD * SS;
    const float* vbase = v + (size_t)bh * SS * DD;
    const int*   mbase = mask + (size_t)b * SS * SS;
    float*       sbase = score + ((size_t)bh * SS + i0) * SS;
    float*       obase = out   + ((size_t)bh * SS + i0) * DD;

    // ---- load Q tile (coalesced float4) ----
    {
        const int c4 = tx * 4;
        #pragma unroll
        for (int r = 0; r < 4; ++r) {
            const int row = ty + 16 * r;
            *(float4*)&Qs[row][c4] = *(const float4*)&qbase[(size_t)row * DD + c4];
        }
    }

    float m_i[4], l_i[4], o_acc[4][4];
    #pragma unroll
    for (int ii = 0; ii < 4; ++ii) {
        m_i[ii] = -3.0e38f;
        l_i[ii] = 0.0f;
        #pragma unroll
        for (int jj = 0; jj < 4; ++jj) o_acc[ii][jj] = 0.0f;
    }

    for (int jt = 0; jt < SS / BN; ++jt) {
        const int j0 = jt * BN;

        __syncthreads();   // prev iteration's PV reads of Ks/Vs/Ps are done
        // ---- stage K tile [d][j] and V tile [j][d] ----
        {
            const int c4 = tx * 4;
            #pragma unroll
            for (int r = 0; r < 4; ++r) {
                const int rr = ty + 16 * r;
                *(float4*)&Ks[rr][c4] = *(const float4*)&kbase[(size_t)rr * SS + j0 + c4];
                *(float4*)&Vs[rr][c4] = *(const float4*)&vbase[(size_t)(j0 + rr) * DD + c4];
            }
        }
        __syncthreads();

        // ---- S tile = Q @ K : acc[ii][jj] = S[ty*4+ii][j0 + tx*4+jj] ----
        float acc[4][4];
        #pragma unroll
        for (int ii = 0; ii < 4; ++ii)
            #pragma unroll
            for (int jj = 0; jj < 4; ++jj) acc[ii][jj] = 0.0f;

        #pragma unroll
        for (int d0 = 0; d0 < DD; d0 += 4) {
            float a_[4][4], b_[4][4];
            #pragma unroll
            for (int ii = 0; ii < 4; ++ii) {
                float4 t = *(const float4*)&Qs[ty * 4 + ii][d0];
                a_[ii][0] = t.x; a_[ii][1] = t.y; a_[ii][2] = t.z; a_[ii][3] = t.w;
            }
            #pragma unroll
            for (int dd = 0; dd < 4; ++dd) {
                float4 t = *(const float4*)&Ks[d0 + dd][tx * 4];
                b_[dd][0] = t.x; b_[dd][1] = t.y; b_[dd][2] = t.z; b_[dd][3] = t.w;
            }
            #pragma unroll
            for (int ii = 0; ii < 4; ++ii)
                #pragma unroll
                for (int jj = 0; jj < 4; ++jj)
                    #pragma unroll
                    for (int dd = 0; dd < 4; ++dd)
                        acc[ii][jj] = fmaf(a_[ii][dd], b_[dd][jj], acc[ii][jj]);
        }

        // ---- scale, mask, write attn_score (output 1) ----
        const int jc0 = j0 + tx * 4;
        #pragma unroll
        for (int ii = 0; ii < 4; ++ii) {
            const int row = ty * 4 + ii;
            int4 mk = *(const int4*)&mbase[(size_t)(i0 + row) * SS + jc0];
            acc[ii][0] = mk.x ? acc[ii][0] * SCALE : MASK_FILL;
            acc[ii][1] = mk.y ? acc[ii][1] * SCALE : MASK_FILL;
            acc[ii][2] = mk.z ? acc[ii][2] * SCALE : MASK_FILL;
            acc[ii][3] = mk.w ? acc[ii][3] * SCALE : MASK_FILL;
            float4 sc = { acc[ii][0], acc[ii][1], acc[ii][2], acc[ii][3] };
            *(float4*)&sbase[(size_t)row * SS + jc0] = sc;
        }

        // ---- online softmax over this tile ----
        #pragma unroll
        for (int ii = 0; ii < 4; ++ii) {
            float pm = fmaxf(fmaxf(acc[ii][0], acc[ii][1]), fmaxf(acc[ii][2], acc[ii][3]));
            #pragma unroll
            for (int off = 8; off >= 1; off >>= 1)
                pm = fmaxf(pm, __shfl_xor(pm, off));
            const float mnew  = fmaxf(m_i[ii], pm);
            const float alpha = __expf(m_i[ii] - mnew);
            float ps = 0.0f;
            #pragma unroll
            for (int jj = 0; jj < 4; ++jj) {
                const float p = __expf(acc[ii][jj] - mnew);
                acc[ii][jj] = p;
                ps += p;
            }
            #pragma unroll
            for (int off = 8; off >= 1; off >>= 1)
                ps += __shfl_xor(ps, off);
            l_i[ii] = l_i[ii] * alpha + ps;
            m_i[ii] = mnew;
            #pragma unroll
            for (int jj = 0; jj < 4; ++jj) o_acc[ii][jj] *= alpha;
            float4 pv = { acc[ii][0], acc[ii][1], acc[ii][2], acc[ii][3] };
            *(float4*)&Ps[ty * 4 + ii][tx * 4] = pv;
        }
        __syncthreads();   // Ps fully written

        // ---- O += P @ V : o_acc[ii][jj] -> O[ty*4+ii][tx*4+jj] ----
        #pragma unroll
        for (int k0 = 0; k0 < BN; k0 += 4) {
            float a_[4][4], b_[4][4];
            #pragma unroll
            for (int ii = 0; ii < 4; ++ii) {
                float4 t = *(const float4*)&Ps[ty * 4 + ii][k0];
                a_[ii][0] = t.x; a_[ii][1] = t.y; a_[ii][2] = t.z; a_[ii][3] = t.w;
            }
            #pragma unroll
            for (int kk = 0; kk < 4; ++kk) {
                float4 t = *(const float4*)&Vs[k0 + kk][tx * 4];
                b_[kk][0] = t.x; b_[kk][1] = t.y; b_[kk][2] = t.z; b_[kk][3] = t.w;
            }
            #pragma unroll
            for (int ii = 0; ii < 4; ++ii)
                #pragma unroll
                for (int jj = 0; jj < 4; ++jj)
                    #pragma unroll
                    for (int kk = 0; kk < 4; ++kk)
                        o_acc[ii][jj] = fmaf(a_[ii][kk], b_[kk][jj], o_acc[ii][jj]);
        }
    }

    // ---- epilogue: O / l, write output (output 0) ----
    #pragma unroll
    for (int ii = 0; ii < 4; ++ii) {
        const float inv = 1.0f / l_i[ii];
        float4 ov = { o_acc[ii][0] * inv, o_acc[ii][1] * inv,
                      o_acc[ii][2] * inv, o_acc[ii][3] * inv };
        *(float4*)&obase[(size_t)(ty * 4 + ii) * DD + tx * 4] = ov;
    }
}

extern "C" void kernel_launch(void* const* d_in, const int* in_sizes, int n_in,
                              void* d_out, int out_size, void* d_ws, size_t ws_size,
                              hipStream_t stream) {
    const float* q    = (const float*)d_in[0];
    const float* k    = (const float*)d_in[1];
    const float* v    = (const float*)d_in[2];
    const int*   mask = (const int*)d_in[3];
    float* out   = (float*)d_out;
    float* score = out + (size_t)BB * HH * SS * DD;   // outputs concatenated: (output, attn_score)

    dim3 grid(SS / BM, BB * HH);
    hipLaunchKernelGGL(sdpa_fused_f32, grid, dim3(NT), 0, stream,
                       q, k, v, mask, out, score);
}